// Round 7
// baseline (256.307 us; speedup 1.0000x reference)
//
#include <hip/hip_runtime.h>
#include <hip/hip_bf16.h>
#include <hip/hip_fp16.h>

#define N_   8
#define T_   300
#define U_   60
#define U1_  61
#define EENC 320
#define NHID 512
#define VOC  128
#define SKROWS 384
#define INV_LN2 1.4426950408889634f
#define LN2 0.6931471805599453f
#define SCALE2 2.8853900817779268f   // 2*log2(e)

typedef __attribute__((ext_vector_type(8))) short bf16x8;
typedef __attribute__((ext_vector_type(4))) float f32x4;

// AS casts via integer round-trip (generic LDS ptr low 32 bits = ds address)
#define AS3U(p) ((__attribute__((address_space(3))) unsigned int*)(unsigned int)(unsigned long long)(p))
#define AS1CU(p) ((const __attribute__((address_space(1))) unsigned int*)(unsigned long long)(p))

__device__ __forceinline__ unsigned short f2bf(float f) {
    unsigned int u = __float_as_uint(f);
    u += 0x7fff + ((u >> 16) & 1);          // RNE
    return (unsigned short)(u >> 16);
}

// log-add-exp in log2 domain
__device__ __forceinline__ float lae2(float x, float y) {
    float m = fmaxf(x, y);
    return m + log2f(1.f + exp2f(-fabsf(x - y)));
}

__device__ __forceinline__ float4 gload16(const void* p) {
    float4 v;
    asm volatile("global_load_dwordx4 %0, %1, off" : "=v"(v) : "v"(p) : "memory");
    return v;
}
#define WAITVM(n) __builtin_amdgcn_s_waitcnt(0x0F70 | (n))

// ---- transpose-convert: WjT[512][320]=bf(Wj^T); WoT2[128][512]=bf(-2*Wo^T); bosum[c]=sum_k Wo[k][c] ----
__global__ __launch_bounds__(256) void convert_w(
    const float* __restrict__ Wj, const float* __restrict__ Wo,
    unsigned short* __restrict__ WjT, unsigned short* __restrict__ WoT2,
    float* __restrict__ bosum)
{
    __shared__ float tile[32][33];
    int bid = blockIdx.x;
    const float* S; unsigned short* D; int k0, c0, K, C; bool isWo;
    if (bid < 160) { S = Wj; D = WjT; K = 320; C = 512; k0 = (bid >> 4) * 32; c0 = (bid & 15) * 32; isWo = false; }
    else { bid -= 160; S = Wo; D = WoT2; K = 512; C = 128; k0 = (bid >> 2) * 32; c0 = (bid & 3) * 32; isWo = true; }
    const int tx = threadIdx.x & 31, ty = threadIdx.x >> 5;
    float part = 0.f;
    #pragma unroll
    for (int i = 0; i < 32; i += 8) {
        float v = S[(k0 + ty + i) * C + c0 + tx];
        tile[ty + i][tx] = v;
        part += v;
    }
    __syncthreads();
    const float mulf = isWo ? -2.f : 1.f;
    #pragma unroll
    for (int i = 0; i < 32; i += 8)
        D[(c0 + ty + i) * K + k0 + tx] = f2bf(mulf * tile[tx][ty + i]);
    if (isWo) atomicAdd(&bosum[c0 + tx], part);
}

// ---- projection GEMM: C[R,512] = (X[R,320] @ Wj + b) * 2log2e ----
__global__ __launch_bounds__(256) void proj_mfma(
    const float* __restrict__ Xe, const float* __restrict__ Xd,
    const unsigned short* __restrict__ BT,
    const float* __restrict__ bj,
    float* __restrict__ Ce, float* __restrict__ Cd)
{
    __shared__ short lA[128 * 64];
    __shared__ short lB[128 * 64];
    int bid = blockIdx.x;
    const float* X; float* Cp; const float* bias; int R;
    if (bid < 76) { X = Xe; Cp = Ce; bias = nullptr; R = N_ * T_; }
    else { bid -= 76; X = Xd; Cp = Cd; bias = bj; R = N_ * U1_; }
    const int tid = threadIdx.x, lane = tid & 63, wave = tid >> 6;
    const int rb = bid >> 2, cb = bid & 3;
    const int rh = wave & 1, ch = wave >> 1;
    const int srow = (tid >> 3) & 31, sg = tid & 7;
    const int frow = lane & 15, fg = lane >> 4, quad = lane >> 4;

    f32x4 acc[4][4];
    f32x4 z = {0.f, 0.f, 0.f, 0.f};
    #pragma unroll
    for (int a = 0; a < 4; ++a)
        #pragma unroll
        for (int b = 0; b < 4; ++b) acc[a][b] = z;

    for (int s = 0; s < 5; ++s) {
        __syncthreads();
        #pragma unroll
        for (int it = 0; it < 4; ++it) {
            int row = srow + it * 32;
            int grow = rb * 128 + row; if (grow >= R) grow = R - 1;
            const float* xp = X + grow * EENC + s * 64 + sg * 8;
            float4 x0 = *(const float4*)xp, x1 = *(const float4*)(xp + 4);
            bf16x8 va;
            va[0] = (short)f2bf(x0.x); va[1] = (short)f2bf(x0.y);
            va[2] = (short)f2bf(x0.z); va[3] = (short)f2bf(x0.w);
            va[4] = (short)f2bf(x1.x); va[5] = (short)f2bf(x1.y);
            va[6] = (short)f2bf(x1.z); va[7] = (short)f2bf(x1.w);
            *(bf16x8*)&lA[row * 64 + ((sg ^ (row & 7)) << 3)] = va;
            int col = row;
            bf16x8 vb = *(const bf16x8*)(BT + (cb * 128 + col) * EENC + s * 64 + sg * 8);
            *(bf16x8*)&lB[col * 64 + ((sg ^ (col & 7)) << 3)] = vb;
        }
        __syncthreads();
        #pragma unroll
        for (int ks = 0; ks < 2; ++ks) {
            int g = fg + ks * 4;
            bf16x8 af[4], bf[4];
            #pragma unroll
            for (int rt = 0; rt < 4; ++rt) {
                int row = rh * 64 + rt * 16 + frow;
                af[rt] = *(const bf16x8*)&lA[row * 64 + ((g ^ (row & 7)) << 3)];
            }
            #pragma unroll
            for (int c = 0; c < 4; ++c) {
                int col = ch * 64 + c * 16 + frow;
                bf[c] = *(const bf16x8*)&lB[col * 64 + ((g ^ (col & 7)) << 3)];
            }
            #pragma unroll
            for (int rt = 0; rt < 4; ++rt)
                #pragma unroll
                for (int c = 0; c < 4; ++c)
                    acc[rt][c] = __builtin_amdgcn_mfma_f32_16x16x32_bf16(af[rt], bf[c], acc[rt][c], 0, 0, 0);
        }
    }
    #pragma unroll
    for (int rt = 0; rt < 4; ++rt) {
        int grow0 = rb * 128 + rh * 64 + rt * 16 + quad * 4;
        #pragma unroll
        for (int c = 0; c < 4; ++c) {
            int col = cb * 128 + ch * 64 + c * 16 + frow;
            float b = bias ? bias[col] : 0.f;
            #pragma unroll
            for (int r = 0; r < 4; ++r) {
                int gr = grow0 + r;
                if (gr < R) Cp[gr * NHID + col] = (acc[rt][c][r] + b) * SCALE2;
            }
        }
    }
}

// ---- joint v2: 1 nt/block; A-frags (sigma) in registers; B double-buffered via global_load_lds ----
// logits = (bo + sum_k Wo) + sum_k sigma_k * (-2 Wo_k);  sigma = rcp(exp2(encp'+decp')+1)
__global__ __launch_bounds__(256, 4) void joint_mfma(
    const float* __restrict__ encp,          // [2400][512], pre-scaled by 2log2e
    const float* __restrict__ decp,          // [488][512], (.. + bj) * 2log2e
    const unsigned short* __restrict__ WoT2, // [128][512] bf16 = -2*Wo^T
    const float* __restrict__ bo, const float* __restrict__ bosum,
    const int* __restrict__ targets,
    unsigned short* __restrict__ Zs)
{
    __shared__ short lB[2][8192];            // 2 x 16 KB, layout [g][col][8]
    __shared__ float bo_s[VOC];
    __shared__ int   lab_s[U_];

    const int tid = threadIdx.x, lane = tid & 63, wave = tid >> 6;
    const int nt = blockIdx.x, n = nt / T_;
    const int t = nt - n * T_;
    if (tid < VOC) bo_s[tid] = bo[tid] + bosum[tid];
    else if (tid < VOC + U_) lab_s[tid - VOC] = targets[n * U_ + (tid - VOC)];

    const int frow = lane & 15, quad = lane >> 4;
    const int ua = min(wave * 16 + frow, U_);
    const float* ep_base = encp + nt * NHID + quad * 8;
    const float* dp_base = decp + (n * U1_ + ua) * NHID + quad * 8;

    // staging indices for this thread's 4 global_load_lds per slice
    int sidx[4], scol[4], sgch[4];
    #pragma unroll
    for (int i = 0; i < 4; ++i) {
        sidx[i] = (wave * 4 + i) * 64 + lane;
        scol[i] = sidx[i] & 127;
        sgch[i] = sidx[i] >> 7;
    }

    f32x4 acc[8];
    f32x4 z = {0.f, 0.f, 0.f, 0.f};
    #pragma unroll
    for (int c = 0; c < 8; ++c) acc[c] = z;

    // stage slice 0 into buf 0
    #pragma unroll
    for (int i = 0; i < 4; ++i)
        __builtin_amdgcn_global_load_lds(AS1CU(WoT2 + scol[i] * NHID + sgch[i] * 8),
                                         AS3U(&lB[0][(wave * 4 + i) * 512]), 16, 0, 0);

    for (int s = 0; s < 8; ++s) {
        __syncthreads();                     // buf[s&1] ready
        const int buf = s & 1;
        if (s < 7) {
            #pragma unroll
            for (int i = 0; i < 4; ++i)
                __builtin_amdgcn_global_load_lds(AS1CU(WoT2 + scol[i] * NHID + (s + 1) * 64 + sgch[i] * 8),
                                                 AS3U(&lB[buf ^ 1][(wave * 4 + i) * 512]), 16, 0, 0);
        }
        #pragma unroll
        for (int h = 0; h < 2; ++h) {
            const int kc = s * 2 + h;
            const float* ep = ep_base + kc * 32;
            const float* dp = dp_base + kc * 32;
            float4 e0 = *(const float4*)ep, e1 = *(const float4*)(ep + 4);
            float4 d0 = *(const float4*)dp, d1 = *(const float4*)(dp + 4);
            float s0 = __builtin_amdgcn_rcpf(__builtin_amdgcn_exp2f(e0.x + d0.x) + 1.f);
            float s1 = __builtin_amdgcn_rcpf(__builtin_amdgcn_exp2f(e0.y + d0.y) + 1.f);
            float s2 = __builtin_amdgcn_rcpf(__builtin_amdgcn_exp2f(e0.z + d0.z) + 1.f);
            float s3 = __builtin_amdgcn_rcpf(__builtin_amdgcn_exp2f(e0.w + d0.w) + 1.f);
            float s4 = __builtin_amdgcn_rcpf(__builtin_amdgcn_exp2f(e1.x + d1.x) + 1.f);
            float s5 = __builtin_amdgcn_rcpf(__builtin_amdgcn_exp2f(e1.y + d1.y) + 1.f);
            float s6 = __builtin_amdgcn_rcpf(__builtin_amdgcn_exp2f(e1.z + d1.z) + 1.f);
            float s7 = __builtin_amdgcn_rcpf(__builtin_amdgcn_exp2f(e1.w + d1.w) + 1.f);
            unsigned b0 = __float_as_uint(s0) + 0x8000u, b1 = __float_as_uint(s1) + 0x8000u;
            unsigned b2 = __float_as_uint(s2) + 0x8000u, b3 = __float_as_uint(s3) + 0x8000u;
            unsigned b4 = __float_as_uint(s4) + 0x8000u, b5 = __float_as_uint(s5) + 0x8000u;
            unsigned b6 = __float_as_uint(s6) + 0x8000u, b7 = __float_as_uint(s7) + 0x8000u;
            union { unsigned u[4]; bf16x8 v; } af;
            af.u[0] = __builtin_amdgcn_perm(b1, b0, 0x07060302);
            af.u[1] = __builtin_amdgcn_perm(b3, b2, 0x07060302);
            af.u[2] = __builtin_amdgcn_perm(b5, b4, 0x07060302);
            af.u[3] = __builtin_amdgcn_perm(b7, b6, 0x07060302);
            #pragma unroll
            for (int c = 0; c < 8; ++c) {
                const bf16x8 bfr = *(const bf16x8*)&lB[buf][(((h * 4 + quad) * 128) + c * 16 + frow) * 8];
                acc[c] = __builtin_amdgcn_mfma_f32_16x16x32_bf16(af.v, bfr, acc[c], 0, 0, 0);
            }
        }
    }

    // ---- epilogue: bias + wave-local per-row LSE over 128 cols; fp16 skew Z output ----
    #pragma unroll
    for (int c = 0; c < 8; ++c) {
        float b = bo_s[c * 16 + frow];
        #pragma unroll
        for (int r = 0; r < 4; ++r) acc[c][r] += b;
    }
    float mx[4], sm[4];
    #pragma unroll
    for (int r = 0; r < 4; ++r) {
        float m = acc[0][r];
        #pragma unroll
        for (int c = 1; c < 8; ++c) m = fmaxf(m, acc[c][r]);
        mx[r] = m;
    }
    #pragma unroll
    for (int off = 1; off < 16; off <<= 1)
        #pragma unroll
        for (int r = 0; r < 4; ++r) mx[r] = fmaxf(mx[r], __shfl_xor(mx[r], off));
    #pragma unroll
    for (int r = 0; r < 4; ++r) {
        float s = 0.f;
        #pragma unroll
        for (int c = 0; c < 8; ++c) s += __expf(acc[c][r] - mx[r]);
        sm[r] = s;
    }
    #pragma unroll
    for (int off = 1; off < 16; off <<= 1)
        #pragma unroll
        for (int r = 0; r < 4; ++r) sm[r] += __shfl_xor(sm[r], off);

    #pragma unroll
    for (int r = 0; r < 4; ++r) {
        float lse = mx[r] + __logf(sm[r]);
        int urow = wave * 16 + quad * 4 + r;
        size_t rowz = (size_t)(n * SKROWS + t + urow + 1) * 64;
        if (urow < U1_ && frow == 0) {
            __half h = __float2half_rn((acc[0][r] - lse) * INV_LN2);
            Zs[(rowz + urow) * 2] = __half_as_ushort(h);
        }
        if (urow < U_) {
            int lab = lab_s[urow];
            if (frow == (lab & 15)) {
                int cw = lab >> 4;
                float pick = acc[0][r];
                #pragma unroll
                for (int c = 1; c < 8; ++c) if (c == cw) pick = acc[c][r];
                __half h = __float2half_rn((pick - lse) * INV_LN2);
                Zs[(rowz + urow + 1) * 2 + 1] = __half_as_ushort(h);
            }
        }
    }
}

// ---- anti-diagonal DP: unchanged from R6 (asm-pinned vmcnt pipeline + L2 warmers) ----
__global__ __launch_bounds__(256) void dp_kernel(
    const unsigned* __restrict__ Z,
    const int* __restrict__ inputs_len, const int* __restrict__ targets_len,
    float* __restrict__ out, float* __restrict__ scrap)
{
    const int tid = threadIdx.x;
    const int nb0 = blockIdx.x * 4;
    if (tid >= 64) {
        const float4* W = (const float4*)(Z + (size_t)nb0 * SKROWS * 64);
        float acc = 0.f;
        const int nv = 4 * SKROWS * 64 / 4;
        for (int i = tid - 64; i < nv; i += 192) acc += W[i].x;
        if (__float_as_uint(acc) == 0x7F123456u) scrap[0] = acc;
        return;
    }
    const int lane = tid;
    const int n  = nb0 + (lane >> 4);
    const int c  = lane & 15;
    const int u0 = c * 4;
    const char* Zn = (const char*)(Z + (size_t)n * SKROWS * 64) + u0 * 4;
    const unsigned len_t = (unsigned)inputs_len[n];
    const int ui = targets_len[n];
    const int ti = (int)len_t - 1;
    const bool u_is0 = (c == 0);

    float a0 = u_is0 ? 0.f : -1e30f;
    float a1 = -1e30f, a2 = -1e30f, a3 = -1e30f;

    float4 zq[8];
    #pragma unroll
    for (int j = 0; j < 8; ++j) zq[j] = gload16(Zn + (size_t)(1 + j) * 256);

    for (int d0 = 1; d0 < 361; d0 += 8) {
        #pragma unroll
        for (int j = 0; j < 8; ++j) {
            const int d = d0 + j;
            WAITVM(7);
            float4 zv = zq[j];
            zq[j] = gload16(Zn + (size_t)(d + 8) * 256);
            const __half2* hz = (const __half2*)&zv;
            float2 w0 = __half22float2(hz[0]);
            float2 w1 = __half22float2(hz[1]);
            float2 w2 = __half22float2(hz[2]);
            float2 w3 = __half22float2(hz[3]);
            float av0 = __shfl_up(a3, 1);
            float e0 = u_is0 ? -1e30f : w0.y;
            float n0 = lae2(a0 + w0.x, av0 + e0);
            float n1 = lae2(a1 + w1.x, a0 + w1.y);
            float n2 = lae2(a2 + w2.x, a1 + w2.y);
            float n3 = lae2(a3 + w3.x, a2 + w3.y);
            a0 = ((unsigned)(d - u0)     < len_t) ? n0 : a0;
            a1 = ((unsigned)(d - u0 - 1) < len_t) ? n1 : a1;
            a2 = ((unsigned)(d - u0 - 2) < len_t) ? n2 : a2;
            a3 = ((unsigned)(d - u0 - 3) < len_t) ? n3 : a3;
        }
    }
    WAITVM(0);
    float av[4] = {a0, a1, a2, a3};
    #pragma unroll
    for (int j = 0; j < 4; ++j)
        if (u0 + j == ui) {
            const __half2* hf = (const __half2*)((const char*)(Z + (size_t)n * SKROWS * 64)
                                                 + ((size_t)(ti + ui + 1) * 64 + ui) * 4);
            float blf = __half22float2(hf[0]).x;
            atomicAdd(out, -(av[j] + blf) * (LN2 / N_));
        }
}

extern "C" void kernel_launch(void* const* d_in, const int* in_sizes, int n_in,
                              void* d_out, int out_size, void* d_ws, size_t ws_size,
                              hipStream_t stream)
{
    const float* enc         = (const float*)d_in[0];
    const float* dec         = (const float*)d_in[1];
    const int*   targets     = (const int*)d_in[2];
    const int*   inputs_len  = (const int*)d_in[3];
    const int*   targets_len = (const int*)d_in[4];
    const float* Wj          = (const float*)d_in[5];
    const float* bj          = (const float*)d_in[6];
    const float* Wo          = (const float*)d_in[7];
    const float* bo          = (const float*)d_in[8];
    float* out = (float*)d_out;

    char* ws = (char*)d_ws;
    float*          encp  = (float*)(ws + 0);                // 2400*512 f32 = 4,915,200
    float*          decp  = (float*)(ws + 4915200);          // 488*512 f32  =   999,424
    unsigned*       Z     = (unsigned*)(ws + 5914624);       // 8*384*64 half2 = 786,432
    unsigned short* WjT   = (unsigned short*)(ws + 6701056); // 512*320 bf16 =   327,680
    unsigned short* WoT2  = (unsigned short*)(ws + 7028736); // 128*512 bf16 =   131,072
    float*          scrap = (float*)(ws + 7159808);          // 64 B
    float*          bosum = (float*)(ws + 7159872);          // 128 f32 = 512 B

    hipMemsetAsync(bosum, 0, VOC * sizeof(float), stream);
    convert_w<<<224, 256, 0, stream>>>(Wj, Wo, WjT, WoT2, bosum);
    proj_mfma<<<92, 256, 0, stream>>>(enc, dec, WjT, bj, encp, decp);
    joint_mfma<<<N_ * T_, 256, 0, stream>>>(encp, decp, WoT2, bo, bosum, targets, (unsigned short*)Z);
    hipMemsetAsync(d_out, 0, sizeof(float), stream);
    dp_kernel<<<2, 256, 0, stream>>>(Z, inputs_len, targets_len, out, scrap);
}

// Round 10
// 235.322 us; speedup vs baseline: 1.0892x; 1.0892x over previous
//
#include <hip/hip_runtime.h>
#include <hip/hip_bf16.h>
#include <hip/hip_fp16.h>

#define N_   8
#define T_   300
#define U_   60
#define U1_  61
#define EENC 320
#define NHID 512
#define VOC  128
#define SKROWS 384
#define INV_LN2 1.4426950408889634f
#define LN2 0.6931471805599453f
#define SCALE2 2.8853900817779268f   // 2*log2(e)

typedef __attribute__((ext_vector_type(8))) short bf16x8;
typedef __attribute__((ext_vector_type(4))) float f32x4;

#define AS3U(p) ((__attribute__((address_space(3))) unsigned int*)(unsigned int)(unsigned long long)(p))
#define AS1CU(p) ((const __attribute__((address_space(1))) unsigned int*)(unsigned long long)(p))

__device__ __forceinline__ unsigned short f2bf(float f) {
    unsigned int u = __float_as_uint(f);
    u += 0x7fff + ((u >> 16) & 1);          // RNE
    return (unsigned short)(u >> 16);
}

__device__ __forceinline__ float lae2(float x, float y) {
    float m = fmaxf(x, y);
    return m + log2f(1.f + exp2f(-fabsf(x - y)));
}

__device__ __forceinline__ float4 gload16(const void* p) {
    float4 v;
    asm volatile("global_load_dwordx4 %0, %1, off" : "=v"(v) : "v"(p) : "memory");
    return v;
}
#define WAITVM(n) __builtin_amdgcn_s_waitcnt(0x0F70 | (n))

// ---- transpose-convert: WjT[512][320]=bf(Wj^T); WoT2[128][512]=bf(-2*Wo^T); bosum[c]=sum_k Wo[k][c] ----
__global__ __launch_bounds__(256) void convert_w(
    const float* __restrict__ Wj, const float* __restrict__ Wo,
    unsigned short* __restrict__ WjT, unsigned short* __restrict__ WoT2,
    float* __restrict__ bosum)
{
    __shared__ float tile[32][33];
    int bid = blockIdx.x;
    const float* S; unsigned short* D; int k0, c0, K, C; bool isWo;
    if (bid < 160) { S = Wj; D = WjT; K = 320; C = 512; k0 = (bid >> 4) * 32; c0 = (bid & 15) * 32; isWo = false; }
    else { bid -= 160; S = Wo; D = WoT2; K = 512; C = 128; k0 = (bid >> 2) * 32; c0 = (bid & 3) * 32; isWo = true; }
    const int tx = threadIdx.x & 31, ty = threadIdx.x >> 5;
    float part = 0.f;
    #pragma unroll
    for (int i = 0; i < 32; i += 8) {
        float v = S[(k0 + ty + i) * C + c0 + tx];
        tile[ty + i][tx] = v;
        part += v;
    }
    __syncthreads();
    const float mulf = isWo ? -2.f : 1.f;
    #pragma unroll
    for (int i = 0; i < 32; i += 8)
        D[(c0 + ty + i) * K + k0 + tx] = f2bf(mulf * tile[tx][ty + i]);
    if (isWo) atomicAdd(&bosum[c0 + tx], part);
}

// ---- projection GEMM, 64x128 tiles: C[R,512] = (X[R,320] @ Wj + b) * 2log2e ----
__global__ __launch_bounds__(256) void proj_mfma(
    const float* __restrict__ Xe, const float* __restrict__ Xd,
    const unsigned short* __restrict__ BT,
    const float* __restrict__ bj,
    float* __restrict__ Ce, float* __restrict__ Cd)
{
    __shared__ short lA[64 * 64];
    __shared__ short lB[128 * 64];
    int bid = blockIdx.x;
    const float* X; float* Cp; const float* bias; int R;
    if (bid < 152) { X = Xe; Cp = Ce; bias = nullptr; R = N_ * T_; }
    else { bid -= 152; X = Xd; Cp = Cd; bias = bj; R = N_ * U1_; }
    const int tid = threadIdx.x, lane = tid & 63, wave = tid >> 6;
    const int rb = bid >> 2, cb = bid & 3;
    const int rh = wave & 1, ch = wave >> 1;
    const int sr = tid >> 3, sg = tid & 7;
    const int frow = lane & 15, fg = lane >> 4, quad = lane >> 4;

    f32x4 acc[2][4];
    f32x4 z = {0.f, 0.f, 0.f, 0.f};
    #pragma unroll
    for (int a = 0; a < 2; ++a)
        #pragma unroll
        for (int b = 0; b < 4; ++b) acc[a][b] = z;

    for (int s = 0; s < 5; ++s) {
        __syncthreads();
        #pragma unroll
        for (int p = 0; p < 2; ++p) {
            int row = sr + p * 32;
            int grow = rb * 64 + row; if (grow >= R) grow = R - 1;
            const float* xp = X + grow * EENC + s * 64 + sg * 8;
            float4 x0 = *(const float4*)xp, x1 = *(const float4*)(xp + 4);
            bf16x8 va;
            va[0] = (short)f2bf(x0.x); va[1] = (short)f2bf(x0.y);
            va[2] = (short)f2bf(x0.z); va[3] = (short)f2bf(x0.w);
            va[4] = (short)f2bf(x1.x); va[5] = (short)f2bf(x1.y);
            va[6] = (short)f2bf(x1.z); va[7] = (short)f2bf(x1.w);
            *(bf16x8*)&lA[row * 64 + ((sg ^ (row & 7)) << 3)] = va;
        }
        #pragma unroll
        for (int p = 0; p < 4; ++p) {
            int col = sr + p * 32;
            bf16x8 vb = *(const bf16x8*)(BT + (cb * 128 + col) * EENC + s * 64 + sg * 8);
            *(bf16x8*)&lB[col * 64 + ((sg ^ (col & 7)) << 3)] = vb;
        }
        __syncthreads();
        #pragma unroll
        for (int ks = 0; ks < 2; ++ks) {
            int g = fg + ks * 4;
            bf16x8 af[2], bf[4];
            #pragma unroll
            for (int rt = 0; rt < 2; ++rt) {
                int row = rh * 32 + rt * 16 + frow;
                af[rt] = *(const bf16x8*)&lA[row * 64 + ((g ^ (row & 7)) << 3)];
            }
            #pragma unroll
            for (int c = 0; c < 4; ++c) {
                int col = ch * 64 + c * 16 + frow;
                bf[c] = *(const bf16x8*)&lB[col * 64 + ((g ^ (col & 7)) << 3)];
            }
            #pragma unroll
            for (int rt = 0; rt < 2; ++rt)
                #pragma unroll
                for (int c = 0; c < 4; ++c)
                    acc[rt][c] = __builtin_amdgcn_mfma_f32_16x16x32_bf16(af[rt], bf[c], acc[rt][c], 0, 0, 0);
        }
    }
    #pragma unroll
    for (int rt = 0; rt < 2; ++rt) {
        int grow0 = rb * 64 + rh * 32 + rt * 16 + quad * 4;
        #pragma unroll
        for (int c = 0; c < 4; ++c) {
            int col = cb * 128 + ch * 64 + c * 16 + frow;
            float b = bias ? bias[col] : 0.f;
            #pragma unroll
            for (int r = 0; r < 4; ++r) {
                int gr = grow0 + r;
                if (gr < R) Cp[gr * NHID + col] = (acc[rt][c][r] + b) * SCALE2;
            }
        }
    }
}

// ---- joint v3: 2 nt/block (128 rows x 128 cols); cooperative sigma->LDS A; B dbuf global_load_lds ----
__global__ __launch_bounds__(256, 3) void joint_mfma(
    const float* __restrict__ encp,
    const float* __restrict__ decp,
    const unsigned short* __restrict__ WoT2,
    const float* __restrict__ bo, const float* __restrict__ bosum,
    const int* __restrict__ targets,
    unsigned short* __restrict__ Zs)
{
    __shared__ short lA[128 * 64];
    __shared__ short lB[2][8192];
    __shared__ float bo_s[VOC];
    __shared__ int   lab_s[U_];

    const int tid = threadIdx.x, lane = tid & 63, wave = tid >> 6;
    const int nt0 = 2 * blockIdx.x, n = nt0 / T_;
    const int t0 = nt0 - n * T_;
    if (tid < VOC) bo_s[tid] = bo[tid] + bosum[tid];
    else if (tid < VOC + U_) lab_s[tid - VOC] = targets[n * U_ + (tid - VOC)];

    const int frow = lane & 15, quad = lane >> 4;
    const int sg = tid & 7, sr = tid >> 3;

    int scol[4], sgch[4];
    #pragma unroll
    for (int i = 0; i < 4; ++i) {
        int sidx = (wave * 4 + i) * 64 + lane;
        scol[i] = sidx & 127;
        sgch[i] = sidx >> 7;
    }

    f32x4 acc[2][8];
    f32x4 z = {0.f, 0.f, 0.f, 0.f};
    #pragma unroll
    for (int rt = 0; rt < 2; ++rt)
        #pragma unroll
        for (int c = 0; c < 8; ++c) acc[rt][c] = z;

    #pragma unroll
    for (int i = 0; i < 4; ++i)
        __builtin_amdgcn_global_load_lds(AS1CU(WoT2 + scol[i] * NHID + sgch[i] * 8),
                                         AS3U(&lB[0][(wave * 4 + i) * 512]), 16, 0, 0);

    for (int s = 0; s < 8; ++s) {
        __syncthreads();
        const int buf = s & 1;
        if (s < 7) {
            #pragma unroll
            for (int i = 0; i < 4; ++i)
                __builtin_amdgcn_global_load_lds(AS1CU(WoT2 + scol[i] * NHID + (s + 1) * 64 + sgch[i] * 8),
                                                 AS3U(&lB[buf ^ 1][(wave * 4 + i) * 512]), 16, 0, 0);
        }
        const float* ep0 = encp + (size_t)nt0 * NHID + s * 64 + sg * 8;
        float4 ea0 = *(const float4*)ep0,          ea1 = *(const float4*)(ep0 + 4);
        float4 eb0 = *(const float4*)(ep0 + NHID), eb1 = *(const float4*)(ep0 + NHID + 4);
        #pragma unroll
        for (int p = 0; p < 4; ++p) {
            int row = sr + p * 32;
            int u = min(row & 63, U_);
            float4 e0 = (p < 2) ? ea0 : eb0;
            float4 e1 = (p < 2) ? ea1 : eb1;
            const float* dp = decp + (size_t)(n * U1_ + u) * NHID + s * 64 + sg * 8;
            float4 d0 = *(const float4*)dp, d1 = *(const float4*)(dp + 4);
            float s0 = __builtin_amdgcn_rcpf(__builtin_amdgcn_exp2f(e0.x + d0.x) + 1.f);
            float s1 = __builtin_amdgcn_rcpf(__builtin_amdgcn_exp2f(e0.y + d0.y) + 1.f);
            float s2 = __builtin_amdgcn_rcpf(__builtin_amdgcn_exp2f(e0.z + d0.z) + 1.f);
            float s3 = __builtin_amdgcn_rcpf(__builtin_amdgcn_exp2f(e0.w + d0.w) + 1.f);
            float s4 = __builtin_amdgcn_rcpf(__builtin_amdgcn_exp2f(e1.x + d1.x) + 1.f);
            float s5 = __builtin_amdgcn_rcpf(__builtin_amdgcn_exp2f(e1.y + d1.y) + 1.f);
            float s6 = __builtin_amdgcn_rcpf(__builtin_amdgcn_exp2f(e1.z + d1.z) + 1.f);
            float s7 = __builtin_amdgcn_rcpf(__builtin_amdgcn_exp2f(e1.w + d1.w) + 1.f);
            unsigned b0 = __float_as_uint(s0) + 0x8000u, b1 = __float_as_uint(s1) + 0x8000u;
            unsigned b2 = __float_as_uint(s2) + 0x8000u, b3 = __float_as_uint(s3) + 0x8000u;
            unsigned b4 = __float_as_uint(s4) + 0x8000u, b5 = __float_as_uint(s5) + 0x8000u;
            unsigned b6 = __float_as_uint(s6) + 0x8000u, b7 = __float_as_uint(s7) + 0x8000u;
            union { unsigned u4[4]; bf16x8 v; } va;
            va.u4[0] = __builtin_amdgcn_perm(b1, b0, 0x07060302);
            va.u4[1] = __builtin_amdgcn_perm(b3, b2, 0x07060302);
            va.u4[2] = __builtin_amdgcn_perm(b5, b4, 0x07060302);
            va.u4[3] = __builtin_amdgcn_perm(b7, b6, 0x07060302);
            *(bf16x8*)&lA[row * 64 + ((sg ^ (row & 7)) << 3)] = va.v;
        }
        __syncthreads();
        #pragma unroll
        for (int h = 0; h < 2; ++h) {
            const int g = h * 4 + quad;
            bf16x8 af[2];
            #pragma unroll
            for (int rt = 0; rt < 2; ++rt) {
                int ar = wave * 32 + rt * 16 + frow;
                af[rt] = *(const bf16x8*)&lA[ar * 64 + ((g ^ (ar & 7)) << 3)];
            }
            #pragma unroll
            for (int c = 0; c < 8; ++c) {
                const bf16x8 bfr = *(const bf16x8*)&lB[buf][(g * 128 + c * 16 + frow) * 8];
                acc[0][c] = __builtin_amdgcn_mfma_f32_16x16x32_bf16(af[0], bfr, acc[0][c], 0, 0, 0);
                acc[1][c] = __builtin_amdgcn_mfma_f32_16x16x32_bf16(af[1], bfr, acc[1][c], 0, 0, 0);
            }
        }
    }

    const int tw = t0 + (wave >> 1);
    #pragma unroll
    for (int rt = 0; rt < 2; ++rt) {
        #pragma unroll
        for (int c = 0; c < 8; ++c) {
            float b = bo_s[c * 16 + frow];
            #pragma unroll
            for (int r = 0; r < 4; ++r) acc[rt][c][r] += b;
        }
        float mx[4], sm[4];
        #pragma unroll
        for (int r = 0; r < 4; ++r) {
            float m = acc[rt][0][r];
            #pragma unroll
            for (int c = 1; c < 8; ++c) m = fmaxf(m, acc[rt][c][r]);
            mx[r] = m;
        }
        #pragma unroll
        for (int off = 1; off < 16; off <<= 1)
            #pragma unroll
            for (int r = 0; r < 4; ++r) mx[r] = fmaxf(mx[r], __shfl_xor(mx[r], off));
        #pragma unroll
        for (int r = 0; r < 4; ++r) {
            float s = 0.f;
            #pragma unroll
            for (int c = 0; c < 8; ++c) s += __expf(acc[rt][c][r] - mx[r]);
            sm[r] = s;
        }
        #pragma unroll
        for (int off = 1; off < 16; off <<= 1)
            #pragma unroll
            for (int r = 0; r < 4; ++r) sm[r] += __shfl_xor(sm[r], off);

        #pragma unroll
        for (int r = 0; r < 4; ++r) {
            float lse = mx[r] + __logf(sm[r]);
            int urow = (wave & 1) * 32 + rt * 16 + quad * 4 + r;
            size_t rowz = (size_t)(n * SKROWS + tw + urow + 1) * 64;
            if (urow < U1_ && frow == 0) {
                __half hh = __float2half_rn((acc[rt][0][r] - lse) * INV_LN2);
                Zs[(rowz + urow) * 2] = __half_as_ushort(hh);
            }
            if (urow < U_) {
                int lab = lab_s[urow];
                if (frow == (lab & 15)) {
                    int cw = lab >> 4;
                    float pick = acc[rt][0][r];
                    #pragma unroll
                    for (int c = 1; c < 8; ++c) if (c == cw) pick = acc[rt][c][r];
                    __half hh = __float2half_rn((pick - lse) * INV_LN2);
                    Zs[(rowz + urow + 1) * 2 + 1] = __half_as_ushort(hh);
                }
            }
        }
    }
}

// ---- anti-diagonal DP: unchanged from R6 (asm-pinned vmcnt pipeline + L2 warmers) ----
__global__ __launch_bounds__(256) void dp_kernel(
    const unsigned* __restrict__ Z,
    const int* __restrict__ inputs_len, const int* __restrict__ targets_len,
    float* __restrict__ out, float* __restrict__ scrap)
{
    const int tid = threadIdx.x;
    const int nb0 = blockIdx.x * 4;
    if (tid >= 64) {
        const float4* W = (const float4*)(Z + (size_t)nb0 * SKROWS * 64);
        float acc = 0.f;
        const int nv = 4 * SKROWS * 64 / 4;
        for (int i = tid - 64; i < nv; i += 192) acc += W[i].x;
        if (__float_as_uint(acc) == 0x7F123456u) scrap[0] = acc;
        return;
    }
    const int lane = tid;
    const int n  = nb0 + (lane >> 4);
    const int c  = lane & 15;
    const int u0 = c * 4;
    const char* Zn = (const char*)(Z + (size_t)n * SKROWS * 64) + u0 * 4;
    const unsigned len_t = (unsigned)inputs_len[n];
    const int ui = targets_len[n];
    const int ti = (int)len_t - 1;
    const bool u_is0 = (c == 0);

    float a0 = u_is0 ? 0.f : -1e30f;
    float a1 = -1e30f, a2 = -1e30f, a3 = -1e30f;

    float4 zq[8];
    #pragma unroll
    for (int j = 0; j < 8; ++j) zq[j] = gload16(Zn + (size_t)(1 + j) * 256);

    for (int d0 = 1; d0 < 361; d0 += 8) {
        #pragma unroll
        for (int j = 0; j < 8; ++j) {
            const int d = d0 + j;
            WAITVM(7);
            float4 zv = zq[j];
            zq[j] = gload16(Zn + (size_t)(d + 8) * 256);
            const __half2* hz = (const __half2*)&zv;
            float2 w0 = __half22float2(hz[0]);
            float2 w1 = __half22float2(hz[1]);
            float2 w2 = __half22float2(hz[2]);
            float2 w3 = __half22float2(hz[3]);
            float av0 = __shfl_up(a3, 1);
            float e0 = u_is0 ? -1e30f : w0.y;
            float n0 = lae2(a0 + w0.x, av0 + e0);
            float n1 = lae2(a1 + w1.x, a0 + w1.y);
            float n2 = lae2(a2 + w2.x, a1 + w2.y);
            float n3 = lae2(a3 + w3.x, a2 + w3.y);
            a0 = ((unsigned)(d - u0)     < len_t) ? n0 : a0;
            a1 = ((unsigned)(d - u0 - 1) < len_t) ? n1 : a1;
            a2 = ((unsigned)(d - u0 - 2) < len_t) ? n2 : a2;
            a3 = ((unsigned)(d - u0 - 3) < len_t) ? n3 : a3;
        }
    }
    WAITVM(0);
    float av[4] = {a0, a1, a2, a3};
    #pragma unroll
    for (int j = 0; j < 4; ++j)
        if (u0 + j == ui) {
            const __half2* hf = (const __half2*)((const char*)(Z + (size_t)n * SKROWS * 64)
                                                 + ((size_t)(ti + ui + 1) * 64 + ui) * 4);
            float blf = __half22float2(hf[0]).x;
            atomicAdd(out, -(av[j] + blf) * (LN2 / N_));
        }
}

extern "C" void kernel_launch(void* const* d_in, const int* in_sizes, int n_in,
                              void* d_out, int out_size, void* d_ws, size_t ws_size,
                              hipStream_t stream)
{
    const float* enc         = (const float*)d_in[0];
    const float* dec         = (const float*)d_in[1];
    const int*   targets     = (const int*)d_in[2];
    const int*   inputs_len  = (const int*)d_in[3];
    const int*   targets_len = (const int*)d_in[4];
    const float* Wj          = (const float*)d_in[5];
    const float* bj          = (const float*)d_in[6];
    const float* Wo          = (const float*)d_in[7];
    const float* bo          = (const float*)d_in[8];
    float* out = (float*)d_out;

    char* ws = (char*)d_ws;
    float*          encp  = (float*)(ws + 0);                // 2400*512 f32 = 4,915,200
    float*          decp  = (float*)(ws + 4915200);          // 488*512 f32  =   999,424
    unsigned*       Z     = (unsigned*)(ws + 5914624);       // 8*384*64 half2 = 786,432
    unsigned short* WjT   = (unsigned short*)(ws + 6701056); // 512*320 bf16 =   327,680
    unsigned short* WoT2  = (unsigned short*)(ws + 7028736); // 128*512 bf16 =   131,072
    float*          scrap = (float*)(ws + 7159808);          // 64 B
    float*          bosum = (float*)(ws + 7159872);          // 128 f32

    hipMemsetAsync(bosum, 0, VOC * sizeof(float), stream);
    convert_w<<<224, 256, 0, stream>>>(Wj, Wo, WjT, WoT2, bosum);
    proj_mfma<<<184, 256, 0, stream>>>(enc, dec, WjT, bj, encp, decp);
    joint_mfma<<<N_ * T_ / 2, 256, 0, stream>>>(encp, decp, WoT2, bo, bosum, targets, (unsigned short*)Z);
    hipMemsetAsync(d_out, 0, sizeof(float), stream);
    dp_kernel<<<2, 256, 0, stream>>>(Z, inputs_len, targets_len, out, scrap);
}

// Round 11
// 228.296 us; speedup vs baseline: 1.1227x; 1.0308x over previous
//
#include <hip/hip_runtime.h>
#include <hip/hip_bf16.h>
#include <hip/hip_fp16.h>

#define N_   8
#define T_   300
#define U_   60
#define U1_  61
#define EENC 320
#define NHID 512
#define VOC  128
#define SKROWS 384
#define INV_LN2 1.4426950408889634f
#define LN2 0.6931471805599453f
#define SCALE2 2.8853900817779268f   // 2*log2(e)

typedef __attribute__((ext_vector_type(8))) short bf16x8;
typedef __attribute__((ext_vector_type(4))) float f32x4;

__device__ __forceinline__ unsigned short f2bf(float f) {
    unsigned int u = __float_as_uint(f);
    u += 0x7fff + ((u >> 16) & 1);          // RNE
    return (unsigned short)(u >> 16);
}

__device__ __forceinline__ float lae2(float x, float y) {
    float m = fmaxf(x, y);
    return m + log2f(1.f + exp2f(-fabsf(x - y)));
}

__device__ __forceinline__ float4 gload16(const void* p) {
    float4 v;
    asm volatile("global_load_dwordx4 %0, %1, off" : "=v"(v) : "v"(p) : "memory");
    return v;
}
#define WAITVM(n) __builtin_amdgcn_s_waitcnt(0x0F70 | (n))

// ---- transpose-convert: WjT[512][320]=bf(Wj^T); WoT2[128][512]=bf(-2*Wo^T); bosum[c]=sum_k Wo[k][c] ----
__global__ __launch_bounds__(256) void convert_w(
    const float* __restrict__ Wj, const float* __restrict__ Wo,
    unsigned short* __restrict__ WjT, unsigned short* __restrict__ WoT2,
    float* __restrict__ bosum)
{
    __shared__ float tile[32][33];
    int bid = blockIdx.x;
    const float* S; unsigned short* D; int k0, c0, K, C; bool isWo;
    if (bid < 160) { S = Wj; D = WjT; K = 320; C = 512; k0 = (bid >> 4) * 32; c0 = (bid & 15) * 32; isWo = false; }
    else { bid -= 160; S = Wo; D = WoT2; K = 512; C = 128; k0 = (bid >> 2) * 32; c0 = (bid & 3) * 32; isWo = true; }
    const int tx = threadIdx.x & 31, ty = threadIdx.x >> 5;
    float part = 0.f;
    #pragma unroll
    for (int i = 0; i < 32; i += 8) {
        float v = S[(k0 + ty + i) * C + c0 + tx];
        tile[ty + i][tx] = v;
        part += v;
    }
    __syncthreads();
    const float mulf = isWo ? -2.f : 1.f;
    #pragma unroll
    for (int i = 0; i < 32; i += 8)
        D[(c0 + ty + i) * K + k0 + tx] = f2bf(mulf * tile[tx][ty + i]);
    if (isWo) atomicAdd(&bosum[c0 + tx], part);
}

// ---- projection GEMM, 64x128 tiles: C[R,512] = (X[R,320] @ Wj + b) * 2log2e ----
__global__ __launch_bounds__(256) void proj_mfma(
    const float* __restrict__ Xe, const float* __restrict__ Xd,
    const unsigned short* __restrict__ BT,
    const float* __restrict__ bj,
    float* __restrict__ Ce, float* __restrict__ Cd)
{
    __shared__ short lA[64 * 64];
    __shared__ short lB[128 * 64];
    int bid = blockIdx.x;
    const float* X; float* Cp; const float* bias; int R;
    if (bid < 152) { X = Xe; Cp = Ce; bias = nullptr; R = N_ * T_; }
    else { bid -= 152; X = Xd; Cp = Cd; bias = bj; R = N_ * U1_; }
    const int tid = threadIdx.x, lane = tid & 63, wave = tid >> 6;
    const int rb = bid >> 2, cb = bid & 3;
    const int rh = wave & 1, ch = wave >> 1;
    const int sr = tid >> 3, sg = tid & 7;
    const int frow = lane & 15, fg = lane >> 4, quad = lane >> 4;

    f32x4 acc[2][4];
    f32x4 z = {0.f, 0.f, 0.f, 0.f};
    #pragma unroll
    for (int a = 0; a < 2; ++a)
        #pragma unroll
        for (int b = 0; b < 4; ++b) acc[a][b] = z;

    for (int s = 0; s < 5; ++s) {
        __syncthreads();
        #pragma unroll
        for (int p = 0; p < 2; ++p) {
            int row = sr + p * 32;
            int grow = rb * 64 + row; if (grow >= R) grow = R - 1;
            const float* xp = X + grow * EENC + s * 64 + sg * 8;
            float4 x0 = *(const float4*)xp, x1 = *(const float4*)(xp + 4);
            bf16x8 va;
            va[0] = (short)f2bf(x0.x); va[1] = (short)f2bf(x0.y);
            va[2] = (short)f2bf(x0.z); va[3] = (short)f2bf(x0.w);
            va[4] = (short)f2bf(x1.x); va[5] = (short)f2bf(x1.y);
            va[6] = (short)f2bf(x1.z); va[7] = (short)f2bf(x1.w);
            *(bf16x8*)&lA[row * 64 + ((sg ^ (row & 7)) << 3)] = va;
        }
        #pragma unroll
        for (int p = 0; p < 4; ++p) {
            int col = sr + p * 32;
            bf16x8 vb = *(const bf16x8*)(BT + (cb * 128 + col) * EENC + s * 64 + sg * 8);
            *(bf16x8*)&lB[col * 64 + ((sg ^ (col & 7)) << 3)] = vb;
        }
        __syncthreads();
        #pragma unroll
        for (int ks = 0; ks < 2; ++ks) {
            int g = fg + ks * 4;
            bf16x8 af[2], bf[4];
            #pragma unroll
            for (int rt = 0; rt < 2; ++rt) {
                int row = rh * 32 + rt * 16 + frow;
                af[rt] = *(const bf16x8*)&lA[row * 64 + ((g ^ (row & 7)) << 3)];
            }
            #pragma unroll
            for (int c = 0; c < 4; ++c) {
                int col = ch * 64 + c * 16 + frow;
                bf[c] = *(const bf16x8*)&lB[col * 64 + ((g ^ (col & 7)) << 3)];
            }
            #pragma unroll
            for (int rt = 0; rt < 2; ++rt)
                #pragma unroll
                for (int c = 0; c < 4; ++c)
                    acc[rt][c] = __builtin_amdgcn_mfma_f32_16x16x32_bf16(af[rt], bf[c], acc[rt][c], 0, 0, 0);
        }
    }
    #pragma unroll
    for (int rt = 0; rt < 2; ++rt) {
        int grow0 = rb * 64 + rh * 32 + rt * 16 + quad * 4;
        #pragma unroll
        for (int c = 0; c < 4; ++c) {
            int col = cb * 128 + ch * 64 + c * 16 + frow;
            float b = bias ? bias[col] : 0.f;
            #pragma unroll
            for (int r = 0; r < 4; ++r) {
                int gr = grow0 + r;
                if (gr < R) Cp[gr * NHID + col] = (acc[rt][c][r] + b) * SCALE2;
            }
        }
    }
}

// ---- joint v4: 2 nt/block; sigma A-staging; R6-style coalesced single-buffer B staging;
//      LDS 33 KB -> 4 blocks/CU for cross-block latency hiding ----
__global__ __launch_bounds__(256, 4) void joint_mfma(
    const float* __restrict__ encp,          // [2400][512], pre-scaled by 2log2e
    const float* __restrict__ decp,          // [488][512], (..+bj)*2log2e
    const unsigned short* __restrict__ WoT2, // [128][512] bf16 = -2*Wo^T
    const float* __restrict__ bo, const float* __restrict__ bosum,
    const int* __restrict__ targets,
    unsigned short* __restrict__ Zs)
{
    __shared__ short lA[128 * 64];           // 16 KB
    __shared__ short lB[128 * 64];           // 16 KB
    __shared__ float bo_s[VOC];
    __shared__ int   lab_s[U_];

    const int tid = threadIdx.x, lane = tid & 63, wave = tid >> 6;
    const int nt0 = 2 * blockIdx.x, n = nt0 / T_;
    const int t0 = nt0 - n * T_;
    if (tid < VOC) bo_s[tid] = bo[tid] + bosum[tid];
    else if (tid < VOC + U_) lab_s[tid - VOC] = targets[n * U_ + (tid - VOC)];

    const int frow = lane & 15, quad = lane >> 4;
    const int sg = tid & 7, sr = tid >> 3;   // sr 0..31, sg = k-octet

    f32x4 acc[2][8];
    f32x4 z = {0.f, 0.f, 0.f, 0.f};
    #pragma unroll
    for (int rt = 0; rt < 2; ++rt)
        #pragma unroll
        for (int c = 0; c < 8; ++c) acc[rt][c] = z;

    for (int s = 0; s < 8; ++s) {            // K=512, slices of 64
        __syncthreads();                     // prev slice's MFMA reads done
        // ---- B staging: coalesced (8 lanes share a row, 128 B contiguous) ----
        #pragma unroll
        for (int p = 0; p < 4; ++p) {
            int col = sr + p * 32;
            bf16x8 vb = *(const bf16x8*)(WoT2 + col * NHID + s * 64 + sg * 8);
            *(bf16x8*)&lB[col * 64 + ((sg ^ (col & 7)) << 3)] = vb;
        }
        // ---- A staging: sigma = rcp(exp2(e'+d')+1), packed to bf16 via v_perm ----
        const float* ep0 = encp + (size_t)nt0 * NHID + s * 64 + sg * 8;
        float4 ea0 = *(const float4*)ep0,          ea1 = *(const float4*)(ep0 + 4);
        float4 eb0 = *(const float4*)(ep0 + NHID), eb1 = *(const float4*)(ep0 + NHID + 4);
        #pragma unroll
        for (int p = 0; p < 4; ++p) {
            int row = sr + p * 32;
            int u = min(row & 63, U_);
            float4 e0 = (p < 2) ? ea0 : eb0;
            float4 e1 = (p < 2) ? ea1 : eb1;
            const float* dp = decp + (size_t)(n * U1_ + u) * NHID + s * 64 + sg * 8;
            float4 d0 = *(const float4*)dp, d1 = *(const float4*)(dp + 4);
            float s0 = __builtin_amdgcn_rcpf(__builtin_amdgcn_exp2f(e0.x + d0.x) + 1.f);
            float s1 = __builtin_amdgcn_rcpf(__builtin_amdgcn_exp2f(e0.y + d0.y) + 1.f);
            float s2 = __builtin_amdgcn_rcpf(__builtin_amdgcn_exp2f(e0.z + d0.z) + 1.f);
            float s3 = __builtin_amdgcn_rcpf(__builtin_amdgcn_exp2f(e0.w + d0.w) + 1.f);
            float s4 = __builtin_amdgcn_rcpf(__builtin_amdgcn_exp2f(e1.x + d1.x) + 1.f);
            float s5 = __builtin_amdgcn_rcpf(__builtin_amdgcn_exp2f(e1.y + d1.y) + 1.f);
            float s6 = __builtin_amdgcn_rcpf(__builtin_amdgcn_exp2f(e1.z + d1.z) + 1.f);
            float s7 = __builtin_amdgcn_rcpf(__builtin_amdgcn_exp2f(e1.w + d1.w) + 1.f);
            unsigned b0 = __float_as_uint(s0) + 0x8000u, b1 = __float_as_uint(s1) + 0x8000u;
            unsigned b2 = __float_as_uint(s2) + 0x8000u, b3 = __float_as_uint(s3) + 0x8000u;
            unsigned b4 = __float_as_uint(s4) + 0x8000u, b5 = __float_as_uint(s5) + 0x8000u;
            unsigned b6 = __float_as_uint(s6) + 0x8000u, b7 = __float_as_uint(s7) + 0x8000u;
            union { unsigned u4[4]; bf16x8 v; } va;
            va.u4[0] = __builtin_amdgcn_perm(b1, b0, 0x07060302);
            va.u4[1] = __builtin_amdgcn_perm(b3, b2, 0x07060302);
            va.u4[2] = __builtin_amdgcn_perm(b5, b4, 0x07060302);
            va.u4[3] = __builtin_amdgcn_perm(b7, b6, 0x07060302);
            *(bf16x8*)&lA[row * 64 + ((sg ^ (row & 7)) << 3)] = va.v;
        }
        __syncthreads();                     // lA/lB ready
        // ---- MFMA: wave covers rows wave*32..+31, all 128 cols ----
        #pragma unroll
        for (int ks = 0; ks < 2; ++ks) {
            const int g = ks * 4 + quad;
            bf16x8 af[2];
            #pragma unroll
            for (int rt = 0; rt < 2; ++rt) {
                int ar = wave * 32 + rt * 16 + frow;
                af[rt] = *(const bf16x8*)&lA[ar * 64 + ((g ^ (ar & 7)) << 3)];
            }
            #pragma unroll
            for (int c = 0; c < 8; ++c) {
                int col = c * 16 + frow;
                const bf16x8 bfr = *(const bf16x8*)&lB[col * 64 + ((g ^ (col & 7)) << 3)];
                acc[0][c] = __builtin_amdgcn_mfma_f32_16x16x32_bf16(af[0], bfr, acc[0][c], 0, 0, 0);
                acc[1][c] = __builtin_amdgcn_mfma_f32_16x16x32_bf16(af[1], bfr, acc[1][c], 0, 0, 0);
            }
        }
    }

    // ---- epilogue: bias + wave-local per-row LSE; fp16 skew Z output ----
    const int tw = t0 + (wave >> 1);
    #pragma unroll
    for (int rt = 0; rt < 2; ++rt) {
        #pragma unroll
        for (int c = 0; c < 8; ++c) {
            float b = bo_s[c * 16 + frow];
            #pragma unroll
            for (int r = 0; r < 4; ++r) acc[rt][c][r] += b;
        }
        float mx[4], sm[4];
        #pragma unroll
        for (int r = 0; r < 4; ++r) {
            float m = acc[rt][0][r];
            #pragma unroll
            for (int c = 1; c < 8; ++c) m = fmaxf(m, acc[rt][c][r]);
            mx[r] = m;
        }
        #pragma unroll
        for (int off = 1; off < 16; off <<= 1)
            #pragma unroll
            for (int r = 0; r < 4; ++r) mx[r] = fmaxf(mx[r], __shfl_xor(mx[r], off));
        #pragma unroll
        for (int r = 0; r < 4; ++r) {
            float ss = 0.f;
            #pragma unroll
            for (int c = 0; c < 8; ++c) ss += __expf(acc[rt][c][r] - mx[r]);
            sm[r] = ss;
        }
        #pragma unroll
        for (int off = 1; off < 16; off <<= 1)
            #pragma unroll
            for (int r = 0; r < 4; ++r) sm[r] += __shfl_xor(sm[r], off);

        #pragma unroll
        for (int r = 0; r < 4; ++r) {
            float lse = mx[r] + __logf(sm[r]);
            int urow = (wave & 1) * 32 + rt * 16 + quad * 4 + r;
            size_t rowz = (size_t)(n * SKROWS + tw + urow + 1) * 64;
            if (urow < U1_ && frow == 0) {
                __half hh = __float2half_rn((acc[rt][0][r] - lse) * INV_LN2);
                Zs[(rowz + urow) * 2] = __half_as_ushort(hh);
            }
            if (urow < U_) {
                int lab = lab_s[urow];
                if (frow == (lab & 15)) {
                    int cw = lab >> 4;
                    float pick = acc[rt][0][r];
                    #pragma unroll
                    for (int c = 1; c < 8; ++c) if (c == cw) pick = acc[rt][c][r];
                    __half hh = __float2half_rn((pick - lse) * INV_LN2);
                    Zs[(rowz + urow + 1) * 2 + 1] = __half_as_ushort(hh);
                }
            }
        }
    }
}

// ---- anti-diagonal DP: unchanged from R6 (asm-pinned vmcnt pipeline + L2 warmers) ----
__global__ __launch_bounds__(256) void dp_kernel(
    const unsigned* __restrict__ Z,
    const int* __restrict__ inputs_len, const int* __restrict__ targets_len,
    float* __restrict__ out, float* __restrict__ scrap)
{
    const int tid = threadIdx.x;
    const int nb0 = blockIdx.x * 4;
    if (tid >= 64) {
        const float4* W = (const float4*)(Z + (size_t)nb0 * SKROWS * 64);
        float acc = 0.f;
        const int nv = 4 * SKROWS * 64 / 4;
        for (int i = tid - 64; i < nv; i += 192) acc += W[i].x;
        if (__float_as_uint(acc) == 0x7F123456u) scrap[0] = acc;
        return;
    }
    const int lane = tid;
    const int n  = nb0 + (lane >> 4);
    const int c  = lane & 15;
    const int u0 = c * 4;
    const char* Zn = (const char*)(Z + (size_t)n * SKROWS * 64) + u0 * 4;
    const unsigned len_t = (unsigned)inputs_len[n];
    const int ui = targets_len[n];
    const int ti = (int)len_t - 1;
    const bool u_is0 = (c == 0);

    float a0 = u_is0 ? 0.f : -1e30f;
    float a1 = -1e30f, a2 = -1e30f, a3 = -1e30f;

    float4 zq[8];
    #pragma unroll
    for (int j = 0; j < 8; ++j) zq[j] = gload16(Zn + (size_t)(1 + j) * 256);

    for (int d0 = 1; d0 < 361; d0 += 8) {
        #pragma unroll
        for (int j = 0; j < 8; ++j) {
            const int d = d0 + j;
            WAITVM(7);
            float4 zv = zq[j];
            zq[j] = gload16(Zn + (size_t)(d + 8) * 256);
            const __half2* hz = (const __half2*)&zv;
            float2 w0 = __half22float2(hz[0]);
            float2 w1 = __half22float2(hz[1]);
            float2 w2 = __half22float2(hz[2]);
            float2 w3 = __half22float2(hz[3]);
            float av0 = __shfl_up(a3, 1);
            float e0 = u_is0 ? -1e30f : w0.y;
            float n0 = lae2(a0 + w0.x, av0 + e0);
            float n1 = lae2(a1 + w1.x, a0 + w1.y);
            float n2 = lae2(a2 + w2.x, a1 + w2.y);
            float n3 = lae2(a3 + w3.x, a2 + w3.y);
            a0 = ((unsigned)(d - u0)     < len_t) ? n0 : a0;
            a1 = ((unsigned)(d - u0 - 1) < len_t) ? n1 : a1;
            a2 = ((unsigned)(d - u0 - 2) < len_t) ? n2 : a2;
            a3 = ((unsigned)(d - u0 - 3) < len_t) ? n3 : a3;
        }
    }
    WAITVM(0);
    float av[4] = {a0, a1, a2, a3};
    #pragma unroll
    for (int j = 0; j < 4; ++j)
        if (u0 + j == ui) {
            const __half2* hf = (const __half2*)((const char*)(Z + (size_t)n * SKROWS * 64)
                                                 + ((size_t)(ti + ui + 1) * 64 + ui) * 4);
            float blf = __half22float2(hf[0]).x;
            atomicAdd(out, -(av[j] + blf) * (LN2 / N_));
        }
}

extern "C" void kernel_launch(void* const* d_in, const int* in_sizes, int n_in,
                              void* d_out, int out_size, void* d_ws, size_t ws_size,
                              hipStream_t stream)
{
    const float* enc         = (const float*)d_in[0];
    const float* dec         = (const float*)d_in[1];
    const int*   targets     = (const int*)d_in[2];
    const int*   inputs_len  = (const int*)d_in[3];
    const int*   targets_len = (const int*)d_in[4];
    const float* Wj          = (const float*)d_in[5];
    const float* bj          = (const float*)d_in[6];
    const float* Wo          = (const float*)d_in[7];
    const float* bo          = (const float*)d_in[8];
    float* out = (float*)d_out;

    char* ws = (char*)d_ws;
    float*          encp  = (float*)(ws + 0);                // 2400*512 f32 = 4,915,200
    float*          decp  = (float*)(ws + 4915200);          // 488*512 f32  =   999,424
    unsigned*       Z     = (unsigned*)(ws + 5914624);       // 8*384*64 half2 = 786,432
    unsigned short* WjT   = (unsigned short*)(ws + 6701056); // 512*320 bf16 =   327,680
    unsigned short* WoT2  = (unsigned short*)(ws + 7028736); // 128*512 bf16 =   131,072
    float*          scrap = (float*)(ws + 7159808);          // 64 B
    float*          bosum = (float*)(ws + 7159872);          // 128 f32

    hipMemsetAsync(bosum, 0, VOC * sizeof(float), stream);
    convert_w<<<224, 256, 0, stream>>>(Wj, Wo, WjT, WoT2, bosum);
    proj_mfma<<<184, 256, 0, stream>>>(enc, dec, WjT, bj, encp, decp);
    joint_mfma<<<N_ * T_ / 2, 256, 0, stream>>>(encp, decp, WoT2, bo, bosum, targets, (unsigned short*)Z);
    hipMemsetAsync(d_out, 0, sizeof(float), stream);
    dp_kernel<<<2, 256, 0, stream>>>(Z, inputs_len, targets_len, out, scrap);
}

// Round 13
// 213.223 us; speedup vs baseline: 1.2021x; 1.0707x over previous
//
#include <hip/hip_runtime.h>
#include <hip/hip_bf16.h>
#include <hip/hip_fp16.h>

#define N_   8
#define T_   300
#define U_   60
#define U1_  61
#define EENC 320
#define NHID 512
#define VOC  128
#define SKROWS 384
#define INV_LN2 1.4426950408889634f
#define LN2 0.6931471805599453f
#define SCALE2 2.8853900817779268f   // 2*log2(e)

typedef __attribute__((ext_vector_type(8))) short bf16x8;
typedef __attribute__((ext_vector_type(4))) float f32x4;

__device__ __forceinline__ unsigned short f2bf(float f) {
    unsigned int u = __float_as_uint(f);
    u += 0x7fff + ((u >> 16) & 1);          // RNE
    return (unsigned short)(u >> 16);
}

// log-add-exp in log2 domain, NaN/inf-proof: fminf returns the non-NaN operand,
// so a rogue inf/NaN operand degrades to max(x,y) instead of NaN.
__device__ __forceinline__ float lae2(float x, float y) {
    float m = fmaxf(x, y);
    float d = fminf(fabsf(x - y), 1e30f);
    return m + log2f(1.f + exp2f(-d));
}

__device__ __forceinline__ float4 gload16(const void* p) {
    float4 v;
    asm volatile("global_load_dwordx4 %0, %1, off" : "=v"(v) : "v"(p) : "memory");
    return v;
}
#define WAITVM(n) __builtin_amdgcn_s_waitcnt(0x0F70 | (n))

// ---- transpose-convert: WjT[512][320]=bf(Wj^T); WoT2[128][512]=bf(-2*Wo^T); bosum[c]=sum_k Wo[k][c] ----
__global__ __launch_bounds__(256) void convert_w(
    const float* __restrict__ Wj, const float* __restrict__ Wo,
    unsigned short* __restrict__ WjT, unsigned short* __restrict__ WoT2,
    float* __restrict__ bosum)
{
    __shared__ float tile[32][33];
    int bid = blockIdx.x;
    const float* S; unsigned short* D; int k0, c0, K, C; bool isWo;
    if (bid < 160) { S = Wj; D = WjT; K = 320; C = 512; k0 = (bid >> 4) * 32; c0 = (bid & 15) * 32; isWo = false; }
    else { bid -= 160; S = Wo; D = WoT2; K = 512; C = 128; k0 = (bid >> 2) * 32; c0 = (bid & 3) * 32; isWo = true; }
    const int tx = threadIdx.x & 31, ty = threadIdx.x >> 5;
    float part = 0.f;
    #pragma unroll
    for (int i = 0; i < 32; i += 8) {
        float v = S[(k0 + ty + i) * C + c0 + tx];
        tile[ty + i][tx] = v;
        part += v;
    }
    __syncthreads();
    const float mulf = isWo ? -2.f : 1.f;
    #pragma unroll
    for (int i = 0; i < 32; i += 8)
        D[(c0 + ty + i) * K + k0 + tx] = f2bf(mulf * tile[tx][ty + i]);
    if (isWo) atomicAdd(&bosum[c0 + tx], part);
}

// ---- projection GEMM, 64x128 tiles: C[R,512] = (X[R,320] @ Wj + b) * 2log2e ----
__global__ __launch_bounds__(256) void proj_mfma(
    const float* __restrict__ Xe, const float* __restrict__ Xd,
    const unsigned short* __restrict__ BT,
    const float* __restrict__ bj,
    float* __restrict__ Ce, float* __restrict__ Cd)
{
    __shared__ short lA[64 * 64];
    __shared__ short lB[128 * 64];
    int bid = blockIdx.x;
    const float* X; float* Cp; const float* bias; int R;
    if (bid < 152) { X = Xe; Cp = Ce; bias = nullptr; R = N_ * T_; }
    else { bid -= 152; X = Xd; Cp = Cd; bias = bj; R = N_ * U1_; }
    const int tid = threadIdx.x, lane = tid & 63, wave = tid >> 6;
    const int rb = bid >> 2, cb = bid & 3;
    const int rh = wave & 1, ch = wave >> 1;
    const int sr = tid >> 3, sg = tid & 7;
    const int frow = lane & 15, fg = lane >> 4, quad = lane >> 4;

    f32x4 acc[2][4];
    f32x4 z = {0.f, 0.f, 0.f, 0.f};
    #pragma unroll
    for (int a = 0; a < 2; ++a)
        #pragma unroll
        for (int b = 0; b < 4; ++b) acc[a][b] = z;

    for (int s = 0; s < 5; ++s) {
        __syncthreads();
        #pragma unroll
        for (int p = 0; p < 2; ++p) {
            int row = sr + p * 32;
            int grow = rb * 64 + row; if (grow >= R) grow = R - 1;
            const float* xp = X + grow * EENC + s * 64 + sg * 8;
            float4 x0 = *(const float4*)xp, x1 = *(const float4*)(xp + 4);
            bf16x8 va;
            va[0] = (short)f2bf(x0.x); va[1] = (short)f2bf(x0.y);
            va[2] = (short)f2bf(x0.z); va[3] = (short)f2bf(x0.w);
            va[4] = (short)f2bf(x1.x); va[5] = (short)f2bf(x1.y);
            va[6] = (short)f2bf(x1.z); va[7] = (short)f2bf(x1.w);
            *(bf16x8*)&lA[row * 64 + ((sg ^ (row & 7)) << 3)] = va;
        }
        #pragma unroll
        for (int p = 0; p < 4; ++p) {
            int col = sr + p * 32;
            bf16x8 vb = *(const bf16x8*)(BT + (cb * 128 + col) * EENC + s * 64 + sg * 8);
            *(bf16x8*)&lB[col * 64 + ((sg ^ (col & 7)) << 3)] = vb;
        }
        __syncthreads();
        #pragma unroll
        for (int ks = 0; ks < 2; ++ks) {
            int g = fg + ks * 4;
            bf16x8 af[2], bf[4];
            #pragma unroll
            for (int rt = 0; rt < 2; ++rt) {
                int row = rh * 32 + rt * 16 + frow;
                af[rt] = *(const bf16x8*)&lA[row * 64 + ((g ^ (row & 7)) << 3)];
            }
            #pragma unroll
            for (int c = 0; c < 4; ++c) {
                int col = ch * 64 + c * 16 + frow;
                bf[c] = *(const bf16x8*)&lB[col * 64 + ((g ^ (col & 7)) << 3)];
            }
            #pragma unroll
            for (int rt = 0; rt < 2; ++rt)
                #pragma unroll
                for (int c = 0; c < 4; ++c)
                    acc[rt][c] = __builtin_amdgcn_mfma_f32_16x16x32_bf16(af[rt], bf[c], acc[rt][c], 0, 0, 0);
        }
    }
    #pragma unroll
    for (int rt = 0; rt < 2; ++rt) {
        int grow0 = rb * 64 + rh * 32 + rt * 16 + quad * 4;
        #pragma unroll
        for (int c = 0; c < 4; ++c) {
            int col = cb * 128 + ch * 64 + c * 16 + frow;
            float b = bias ? bias[col] : 0.f;
            #pragma unroll
            for (int r = 0; r < 4; ++r) {
                int gr = grow0 + r;
                if (gr < R) Cp[gr * NHID + col] = (acc[rt][c][r] + b) * SCALE2;
            }
        }
    }
}

// ---- joint v5: 512 thr, 4 nt/block (600 blocks); dec loaded once reused 4x; single-buffer LDS ----
__global__ __launch_bounds__(512, 4) void joint_mfma(
    const float* __restrict__ encp,          // [2400][512], pre-scaled by 2log2e
    const float* __restrict__ decp,          // [488][512], (..+bj)*2log2e
    const unsigned short* __restrict__ WoT2, // [128][512] bf16 = -2*Wo^T
    const float* __restrict__ bo, const float* __restrict__ bosum,
    const int* __restrict__ targets,
    unsigned short* __restrict__ Zs)
{
    __shared__ short lA[256 * 64];           // 32 KB (4 nt x 64 rows)
    __shared__ short lB[128 * 64];           // 16 KB
    __shared__ float bo_s[VOC];
    __shared__ int   lab_s[U_];

    const int tid = threadIdx.x, lane = tid & 63, wave = tid >> 6;  // wave 0..7
    const int nt0 = 4 * blockIdx.x, n = nt0 / T_;  // 300 % 4 == 0 -> no batch straddle
    const int t0 = nt0 - n * T_;
    if (tid < VOC) bo_s[tid] = bo[tid] + bosum[tid];
    else if (tid < VOC + U_) lab_s[tid - VOC] = targets[n * U_ + (tid - VOC)];

    const int frow = lane & 15, quad = lane >> 4;
    const int sg = tid & 7, sr = tid >> 3;   // sr 0..63, k-octet sg

    f32x4 acc[2][8];
    f32x4 z = {0.f, 0.f, 0.f, 0.f};
    #pragma unroll
    for (int rt = 0; rt < 2; ++rt)
        #pragma unroll
        for (int c = 0; c < 8; ++c) acc[rt][c] = z;

    const int ua = min(sr, U_);
    const float* dbase = decp + (size_t)(n * U1_ + ua) * NHID + sg * 8;
    const float* ebase = encp + (size_t)nt0 * NHID + sg * 8;

    for (int s = 0; s < 8; ++s) {            // K=512, slices of 64
        __syncthreads();                     // prev MFMA done reading lA/lB
        // ---- B staging: 2 passes, coalesced ----
        #pragma unroll
        for (int p = 0; p < 2; ++p) {
            int col = sr + p * 64;
            bf16x8 vb = *(const bf16x8*)(WoT2 + col * NHID + s * 64 + sg * 8);
            *(bf16x8*)&lB[col * 64 + ((sg ^ (col & 7)) << 3)] = vb;
        }
        // ---- dec chunk: ONE load pair, shared by all 4 nt ----
        const float* dp = dbase + s * 64;
        float4 d0 = *(const float4*)dp, d1 = *(const float4*)(dp + 4);
        // ---- A sigma staging: 4 passes, one nt each; row = sr + p*64 ----
        #pragma unroll
        for (int p = 0; p < 4; ++p) {
            const float* ep = ebase + (size_t)p * NHID + s * 64;
            float4 e0 = *(const float4*)ep, e1 = *(const float4*)(ep + 4);
            float s0 = __builtin_amdgcn_rcpf(__builtin_amdgcn_exp2f(e0.x + d0.x) + 1.f);
            float s1 = __builtin_amdgcn_rcpf(__builtin_amdgcn_exp2f(e0.y + d0.y) + 1.f);
            float s2 = __builtin_amdgcn_rcpf(__builtin_amdgcn_exp2f(e0.z + d0.z) + 1.f);
            float s3 = __builtin_amdgcn_rcpf(__builtin_amdgcn_exp2f(e0.w + d0.w) + 1.f);
            float s4 = __builtin_amdgcn_rcpf(__builtin_amdgcn_exp2f(e1.x + d1.x) + 1.f);
            float s5 = __builtin_amdgcn_rcpf(__builtin_amdgcn_exp2f(e1.y + d1.y) + 1.f);
            float s6 = __builtin_amdgcn_rcpf(__builtin_amdgcn_exp2f(e1.z + d1.z) + 1.f);
            float s7 = __builtin_amdgcn_rcpf(__builtin_amdgcn_exp2f(e1.w + d1.w) + 1.f);
            unsigned b0 = __float_as_uint(s0) + 0x8000u, b1 = __float_as_uint(s1) + 0x8000u;
            unsigned b2 = __float_as_uint(s2) + 0x8000u, b3 = __float_as_uint(s3) + 0x8000u;
            unsigned b4 = __float_as_uint(s4) + 0x8000u, b5 = __float_as_uint(s5) + 0x8000u;
            unsigned b6 = __float_as_uint(s6) + 0x8000u, b7 = __float_as_uint(s7) + 0x8000u;
            union { unsigned u4[4]; bf16x8 v; } va;
            va.u4[0] = __builtin_amdgcn_perm(b1, b0, 0x07060302);
            va.u4[1] = __builtin_amdgcn_perm(b3, b2, 0x07060302);
            va.u4[2] = __builtin_amdgcn_perm(b5, b4, 0x07060302);
            va.u4[3] = __builtin_amdgcn_perm(b7, b6, 0x07060302);
            int row = sr + p * 64;
            *(bf16x8*)&lA[row * 64 + ((sg ^ (row & 7)) << 3)] = va.v;
        }
        __syncthreads();                     // lA/lB ready
        // ---- MFMA: wave covers rows wave*32..+31, all 128 cols ----
        #pragma unroll
        for (int ks = 0; ks < 2; ++ks) {
            const int g = ks * 4 + quad;
            bf16x8 af[2];
            #pragma unroll
            for (int rt = 0; rt < 2; ++rt) {
                int ar = wave * 32 + rt * 16 + frow;
                af[rt] = *(const bf16x8*)&lA[ar * 64 + ((g ^ (ar & 7)) << 3)];
            }
            #pragma unroll
            for (int c = 0; c < 8; ++c) {
                int col = c * 16 + frow;
                const bf16x8 bfr = *(const bf16x8*)&lB[col * 64 + ((g ^ (col & 7)) << 3)];
                acc[0][c] = __builtin_amdgcn_mfma_f32_16x16x32_bf16(af[0], bfr, acc[0][c], 0, 0, 0);
                acc[1][c] = __builtin_amdgcn_mfma_f32_16x16x32_bf16(af[1], bfr, acc[1][c], 0, 0, 0);
            }
        }
    }

    // ---- epilogue: bias + wave-local per-row LSE; fp16 skew Z output ----
    #pragma unroll
    for (int rt = 0; rt < 2; ++rt) {
        #pragma unroll
        for (int c = 0; c < 8; ++c) {
            float b = bo_s[c * 16 + frow];
            #pragma unroll
            for (int r = 0; r < 4; ++r) acc[rt][c][r] += b;
        }
        float mx[4], sm[4];
        #pragma unroll
        for (int r = 0; r < 4; ++r) {
            float m = acc[rt][0][r];
            #pragma unroll
            for (int c = 1; c < 8; ++c) m = fmaxf(m, acc[rt][c][r]);
            mx[r] = m;
        }
        #pragma unroll
        for (int off = 1; off < 16; off <<= 1)
            #pragma unroll
            for (int r = 0; r < 4; ++r) mx[r] = fmaxf(mx[r], __shfl_xor(mx[r], off));
        #pragma unroll
        for (int r = 0; r < 4; ++r) {
            float ss = 0.f;
            #pragma unroll
            for (int c = 0; c < 8; ++c) ss += __expf(acc[rt][c][r] - mx[r]);
            sm[r] = ss;
        }
        #pragma unroll
        for (int off = 1; off < 16; off <<= 1)
            #pragma unroll
            for (int r = 0; r < 4; ++r) sm[r] += __shfl_xor(sm[r], off);

        #pragma unroll
        for (int r = 0; r < 4; ++r) {
            float lse = mx[r] + __logf(sm[r]);
            int row = wave * 32 + rt * 16 + quad * 4 + r;    // 0..255
            int urow = row & 63, ntl = row >> 6;
            size_t rowz = (size_t)(n * SKROWS + t0 + ntl + urow + 1) * 64;
            if (urow < U1_ && frow == 0) {
                __half hh = __float2half_rn((acc[rt][0][r] - lse) * INV_LN2);
                Zs[(rowz + urow) * 2] = __half_as_ushort(hh);
            }
            if (urow < U_) {
                int lab = lab_s[urow];
                if (frow == (lab & 15)) {
                    int cw = lab >> 4;
                    float pick = acc[rt][0][r];
                    #pragma unroll
                    for (int c = 1; c < 8; ++c) if (c == cw) pick = acc[rt][c][r];
                    __half hh = __float2half_rn((pick - lse) * INV_LN2);
                    Zs[(rowz + urow + 1) * 2 + 1] = __half_as_ushort(hh);
                }
            }
        }
    }
}

// ---- dp v3b: single block, 512 thr; waves 0-1 compute 8 batches (shfl_up neighbor),
//      waves 2-7 warm L2; LDS loss reduce, plain store ----
__global__ __launch_bounds__(512) void dp_kernel(
    const unsigned* __restrict__ Z,
    const int* __restrict__ inputs_len, const int* __restrict__ targets_len,
    float* __restrict__ out)
{
    __shared__ float losses[N_];
    __shared__ float guard;
    const int tid = threadIdx.x;
    if (tid >= 128) {                        // L2 warmers
        const float4* W = (const float4*)Z;
        float acc = 0.f;
        const int nv = N_ * SKROWS * 16;     // float4 count
        for (int i = tid - 128; i < nv; i += 384) acc += W[i].x;
        if (__float_as_uint(acc) == 0x7F123456u) guard = acc;   // DCE guard, never true
    } else {
        const int n  = tid >> 4;
        const int c  = tid & 15;
        const int u0 = c * 4;
        const char* Zn = (const char*)(Z + (size_t)n * SKROWS * 64) + u0 * 4;
        const unsigned len_t = (unsigned)inputs_len[n];
        const int ui = targets_len[n];
        const int ti = (int)len_t - 1;
        const bool u_is0 = (c == 0);

        float a0 = u_is0 ? 0.f : -1e30f;
        float a1 = -1e30f, a2 = -1e30f, a3 = -1e30f;

        float4 zq[8];
        #pragma unroll
        for (int j = 0; j < 8; ++j) zq[j] = gload16(Zn + (size_t)(1 + j) * 256);

        for (int d0 = 1; d0 < 361; d0 += 8) {
            #pragma unroll
            for (int j = 0; j < 8; ++j) {
                const int d = d0 + j;
                WAITVM(7);
                float4 zv = zq[j];
                zq[j] = gload16(Zn + (size_t)(d + 8) * 256);
                const __half2* hz = (const __half2*)&zv;
                float2 w0 = __half22float2(hz[0]);
                float2 w1 = __half22float2(hz[1]);
                float2 w2 = __half22float2(hz[2]);
                float2 w3 = __half22float2(hz[3]);
                // neighbor a3 from lane-1 (proven R11 construct; cross-batch lanes
                // have c==0 and are neutralized by e0 = -1e30)
                float av0 = __shfl_up(a3, 1);
                float e0 = u_is0 ? -1e30f : w0.y;
                float n0 = lae2(a0 + w0.x, av0 + e0);
                float n1 = lae2(a1 + w1.x, a0 + w1.y);
                float n2 = lae2(a2 + w2.x, a1 + w2.y);
                float n3 = lae2(a3 + w3.x, a2 + w3.y);
                a0 = ((unsigned)(d - u0)     < len_t) ? n0 : a0;
                a1 = ((unsigned)(d - u0 - 1) < len_t) ? n1 : a1;
                a2 = ((unsigned)(d - u0 - 2) < len_t) ? n2 : a2;
                a3 = ((unsigned)(d - u0 - 3) < len_t) ? n3 : a3;
            }
        }
        WAITVM(0);
        float av[4] = {a0, a1, a2, a3};
        #pragma unroll
        for (int j = 0; j < 4; ++j)
            if (u0 + j == ui) {
                const __half2* hf = (const __half2*)((const char*)(Z + (size_t)n * SKROWS * 64)
                                                     + ((size_t)(ti + ui + 1) * 64 + ui) * 4);
                float blf = __half22float2(hf[0]).x;
                losses[n] = -(av[j] + blf) * LN2;
            }
    }
    __syncthreads();
    if (tid == 0) {
        float s = 0.f;
        #pragma unroll
        for (int i = 0; i < N_; ++i) s += losses[i];
        out[0] = s * (1.0f / N_);
    }
}

extern "C" void kernel_launch(void* const* d_in, const int* in_sizes, int n_in,
                              void* d_out, int out_size, void* d_ws, size_t ws_size,
                              hipStream_t stream)
{
    const float* enc         = (const float*)d_in[0];
    const float* dec         = (const float*)d_in[1];
    const int*   targets     = (const int*)d_in[2];
    const int*   inputs_len  = (const int*)d_in[3];
    const int*   targets_len = (const int*)d_in[4];
    const float* Wj          = (const float*)d_in[5];
    const float* bj          = (const float*)d_in[6];
    const float* Wo          = (const float*)d_in[7];
    const float* bo          = (const float*)d_in[8];
    float* out = (float*)d_out;

    char* ws = (char*)d_ws;
    float*          encp  = (float*)(ws + 0);                // 2400*512 f32 = 4,915,200
    float*          decp  = (float*)(ws + 4915200);          // 488*512 f32  =   999,424
    unsigned*       Z     = (unsigned*)(ws + 5914624);       // 8*384*64 half2 = 786,432
    unsigned short* WjT   = (unsigned short*)(ws + 6701056); // 512*320 bf16 =   327,680
    unsigned short* WoT2  = (unsigned short*)(ws + 7028736); // 128*512 bf16 =   131,072
    float*          bosum = (float*)(ws + 7159872);          // 128 f32

    hipMemsetAsync(bosum, 0, VOC * sizeof(float), stream);
    convert_w<<<224, 256, 0, stream>>>(Wj, Wo, WjT, WoT2, bosum);
    proj_mfma<<<184, 256, 0, stream>>>(enc, dec, WjT, bj, encp, decp);
    joint_mfma<<<600, 512, 0, stream>>>(encp, decp, WoT2, bo, bosum, targets, (unsigned short*)Z);
    dp_kernel<<<1, 512, 0, stream>>>(Z, inputs_len, targets_len, out);
}